// Round 1
// baseline (4703.770 us; speedup 1.0000x reference)
//
#include <hip/hip_runtime.h>

#define Bn 8
#define Sn 4096
#define Dn 1024
#define Mn 32
#define Kk 3
#define Rn 64
#define BSn (Bn*Sn)

typedef unsigned short u16;
typedef short short8 __attribute__((ext_vector_type(8)));
typedef float f32x4 __attribute__((ext_vector_type(4)));

__device__ __forceinline__ u16 f2bf(float f){
  unsigned u = __builtin_bit_cast(unsigned, f);
  u += 0x7fffu + ((u >> 16) & 1u);          // RNE
  return (u16)(u >> 16);
}
__device__ __forceinline__ float bf2f(u16 h){
  unsigned u = ((unsigned)h) << 16;
  return __builtin_bit_cast(float, u);
}

__device__ __forceinline__ float2 block_sum2(float a, float b, float* red){
  #pragma unroll
  for (int off = 32; off > 0; off >>= 1){
    a += __shfl_down(a, off, 64);
    b += __shfl_down(b, off, 64);
  }
  int lane = threadIdx.x & 63, w = threadIdx.x >> 6;
  if (lane == 0){ red[w] = a; red[4+w] = b; }
  __syncthreads();
  float2 r;
  r.x = red[0]+red[1]+red[2]+red[3];
  r.y = red[4]+red[5]+red[6]+red[7];
  __syncthreads();
  return r;
}

__device__ __forceinline__ float3 block_sum3(float a, float b, float c, float* red){
  #pragma unroll
  for (int off = 32; off > 0; off >>= 1){
    a += __shfl_down(a, off, 64);
    b += __shfl_down(b, off, 64);
    c += __shfl_down(c, off, 64);
  }
  int lane = threadIdx.x & 63, w = threadIdx.x >> 6;
  if (lane == 0){ red[w] = a; red[4+w] = b; red[8+w] = c; }
  __syncthreads();
  float3 r;
  r.x = red[0]+red[1]+red[2]+red[3];
  r.y = red[4]+red[5]+red[6]+red[7];
  r.z = red[8]+red[9]+red[10]+red[11];
  __syncthreads();
  return r;
}

// ---------------- scores = pt_hidden @ anchor_w + anchor_b ----------------
__global__ __launch_bounds__(256) void k_scores(const float* __restrict__ pt,
    const float* __restrict__ aw, const float* __restrict__ ab, float* __restrict__ scores){
  int lane = threadIdx.x & 63, w = threadIdx.x >> 6;
  int row = blockIdx.x * 4 + w;
  const float4* x  = (const float4*)(pt + (size_t)row * Dn);
  const float4* wv = (const float4*)aw;
  float acc = 0.f;
  #pragma unroll
  for (int c = 0; c < 4; c++){
    int i = c * 64 + lane;
    float4 a = x[i], b = wv[i];
    acc += a.x*b.x + a.y*b.y + a.z*b.z + a.w*b.w;
  }
  #pragma unroll
  for (int off = 32; off > 0; off >>= 1) acc += __shfl_down(acc, off, 64);
  if (lane == 0) scores[row] = acc + ab[0];
}

// ---------------- top-3 per batch ----------------
__global__ __launch_bounds__(256) void k_top3(const float* __restrict__ scores, int* __restrict__ aidx){
  __shared__ float tv[256*3];
  __shared__ int   ti[256*3];
  int b = blockIdx.x, t = threadIdx.x;
  float v[3] = {-1e38f, -1e38f, -1e38f};
  int  id[3] = {0x7fffffff, 0x7fffffff, 0x7fffffff};
  for (int s = t; s < Sn; s += 256){
    float sc = scores[b*Sn + s];
    if (sc > v[0] || (sc == v[0] && s < id[0])){ v[2]=v[1]; id[2]=id[1]; v[1]=v[0]; id[1]=id[0]; v[0]=sc; id[0]=s; }
    else if (sc > v[1] || (sc == v[1] && s < id[1])){ v[2]=v[1]; id[2]=id[1]; v[1]=sc; id[1]=s; }
    else if (sc > v[2] || (sc == v[2] && s < id[2])){ v[2]=sc; id[2]=s; }
  }
  for (int j = 0; j < 3; j++){ tv[t*3+j] = v[j]; ti[t*3+j] = id[j]; }
  __syncthreads();
  if (t == 0){
    float bv[3] = {-1e38f, -1e38f, -1e38f};
    int   bi[3] = {0x7fffffff, 0x7fffffff, 0x7fffffff};
    for (int c = 0; c < 256*3; c++){
      float sc = tv[c]; int ii = ti[c];
      if (sc > bv[0] || (sc == bv[0] && ii < bi[0])){ bv[2]=bv[1]; bi[2]=bi[1]; bv[1]=bv[0]; bi[1]=bi[0]; bv[0]=sc; bi[0]=ii; }
      else if (sc > bv[1] || (sc == bv[1] && ii < bi[1])){ bv[2]=bv[1]; bi[2]=bi[1]; bv[1]=sc; bi[1]=ii; }
      else if (sc > bv[2] || (sc == bv[2] && ii < bi[2])){ bv[2]=sc; bi[2]=ii; }
    }
    for (int j = 0; j < 3; j++) aidx[b*3+j] = bi[j];
  }
}

// ---------------- adapter: per (b,k) anchor -> translated vector + spread 1/Z ----------------
__global__ __launch_bounds__(256) void k_adapter(const float* __restrict__ pt,
    const float* __restrict__ cent, const float* __restrict__ ta, const float* __restrict__ tb,
    const float* __restrict__ pp, const int* __restrict__ aidx,
    float* __restrict__ transl, float* __restrict__ invZ){
  __shared__ float a_lds[Dn];
  __shared__ float logitv[Mn];
  __shared__ float wts[Mn];
  __shared__ float lowv[Rn];
  __shared__ float lred[4][Rn];
  __shared__ float red[12];
  int blk = blockIdx.x; int b = blk / Kk, k = blk % Kk;
  int t = threadIdx.x;
  int p = aidx[b*Kk + k];
  const float* arow = pt + ((size_t)b*Sn + p) * Dn;
  for (int d = t; d < Dn; d += 256) a_lds[d] = arow[d];
  __syncthreads();
  // ||a||
  float ss = 0.f;
  for (int d = t; d < Dn; d += 256){ float v = a_lds[d]; ss += v*v; }
  float2 rr0 = block_sum2(ss, 0.f, red);
  float na = fmaxf(sqrtf(rr0.x), 1e-6f);
  // centroid logits: wave w handles 8 modes
  int lane = t & 63, w = t >> 6;
  for (int mi = 0; mi < 8; mi++){
    int m = w*8 + mi;
    const float* c = cent + (size_t)m * Dn;
    float dt = 0.f, cs = 0.f;
    for (int d = lane; d < Dn; d += 64){ float cv = c[d]; dt += a_lds[d]*cv; cs += cv*cv; }
    #pragma unroll
    for (int off = 32; off > 0; off >>= 1){ dt += __shfl_down(dt, off, 64); cs += __shfl_down(cs, off, 64); }
    if (lane == 0){ float nc = fmaxf(sqrtf(cs), 1e-6f); logitv[m] = dt / (na * nc); }
  }
  __syncthreads();
  if (t == 0){
    float mx = -1e30f;
    for (int m = 0; m < Mn; m++) mx = fmaxf(mx, logitv[m]);
    float sm = 0.f;
    for (int m = 0; m < Mn; m++){ float e = expf(logitv[m]-mx); wts[m] = e; sm += e; }
    float inv = 1.f / sm;
    for (int m = 0; m < Mn; m++) wts[m] *= inv;
  }
  __syncthreads();
  // spread normalizer Z (softmax over masked window; max logit = 0 at s=p)
  {
    float zp = 0.f; float ppp = pp[p];
    for (int s2 = t; s2 < Sn; s2 += 256){
      float dd = fabsf(pp[s2] - ppp);
      if (dd <= 8.0f) zp += expf(-dd * 0.125f);
    }
    float2 zr = block_sum2(zp, 0.f, red);
    if (t == 0) invZ[b*Kk + k] = 1.f / zr.x;
  }
  // low[r] = sum_m w_m * (a . trans_a[m,:,r])
  {
    int r = t & 63, g = t >> 6;
    float acc = 0.f;
    for (int m = 0; m < Mn; m++){
      const float* base = ta + ((size_t)m * Dn * Rn) + r;
      float tm = 0.f;
      for (int d = g; d < Dn; d += 4) tm += a_lds[d] * base[(size_t)d * Rn];
      acc += wts[m] * tm;
    }
    lred[g][r] = acc;
    __syncthreads();
    if (t < Rn) lowv[t] = lred[0][t] + lred[1][t] + lred[2][t] + lred[3][t];
    __syncthreads();
  }
  // translated[d] = sum_m w_m * (trans_b[m,d,:] . low)
  float* outp = transl + ((size_t)(b*Kk + k)) * Dn;
  for (int d = t; d < Dn; d += 256){
    float acc = 0.f;
    for (int m = 0; m < Mn; m++){
      const float4* brow = (const float4*)(tb + (((size_t)m * Dn + d) * Rn));
      float tr = 0.f;
      #pragma unroll
      for (int q = 0; q < 16; q++){
        float4 v = brow[q];
        tr += v.x*lowv[q*4] + v.y*lowv[q*4+1] + v.z*lowv[q*4+2] + v.w*lowv[q*4+3];
      }
      acc += wts[m] * tr;
    }
    outp[d] = acc;
  }
}

// ---------------- transpose f32 [Ks][1024] -> bf16 [1024][Ks] ----------------
__global__ __launch_bounds__(256) void k_transpose(const float* __restrict__ src,
    u16* __restrict__ dst, int Ks){
  __shared__ float tile[32][33];
  int kb = blockIdx.x * 32, nb = blockIdx.y * 32;
  int tx = threadIdx.x & 31, ty = threadIdx.x >> 5;   // ty in 0..7
  #pragma unroll
  for (int r = 0; r < 32; r += 8)
    tile[ty+r][tx] = src[(size_t)(kb+ty+r) * Dn + nb + tx];
  __syncthreads();
  #pragma unroll
  for (int r = 0; r < 32; r += 8)
    dst[(size_t)(nb+ty+r) * Ks + kb + tx] = f2bf(tile[tx][ty+r]);
}

// ---------------- per-row: spread update + 3 LN + gate ----------------
__global__ __launch_bounds__(256) void k_rows(
    const float* __restrict__ ts, const float* __restrict__ pt,
    const float* __restrict__ stab, const float* __restrict__ transl,
    const int* __restrict__ aidx, const float* __restrict__ invZ,
    const float* __restrict__ pp,
    const float* __restrict__ og, const float* __restrict__ ob,
    const float* __restrict__ tgp, const float* __restrict__ tbp,
    const float* __restrict__ pgp, const float* __restrict__ pbp,
    float* __restrict__ ts_aug_out, u16* __restrict__ Xcat, float* __restrict__ gate){
  __shared__ float red[12];
  int row = blockIdx.x; int b = row >> 12; int s = row & 4095;
  int t = threadIdx.x;
  size_t base = (size_t)row * Dn;
  const float4 xin = *(const float4*)(ts + base + 4*t);
  float x0 = xin.x, x1 = xin.y, x2 = xin.z, x3 = xin.w;
  float pps = pp[s];
  for (int k = 0; k < Kk; k++){
    int p = aidx[b*Kk + k];
    float dd = fabsf(pps - pp[p]);
    if (dd <= 8.0f){
      float coef = expf(-dd * 0.125f) * invZ[b*Kk + k];
      const float4 tr = *(const float4*)(transl + ((size_t)(b*Kk + k)) * Dn + 4*t);
      x0 += coef*tr.x; x1 += coef*tr.y; x2 += coef*tr.z; x3 += coef*tr.w;
    }
  }
  // LN1 (out_norm) -> ts_aug (written to d_out ts half)
  float2 r = block_sum2(x0+x1+x2+x3, x0*x0+x1*x1+x2*x2+x3*x3, red);
  float mu = r.x * (1.f/Dn); float var = r.y * (1.f/Dn) - mu*mu;
  float rs = 1.f / sqrtf(var + 1e-5f);
  float4 g4 = *(const float4*)(og + 4*t), b4 = *(const float4*)(ob + 4*t);
  float a0 = (x0-mu)*rs*g4.x + b4.x;
  float a1 = (x1-mu)*rs*g4.y + b4.y;
  float a2 = (x2-mu)*rs*g4.z + b4.z;
  float a3 = (x3-mu)*rs*g4.w + b4.w;
  float4 sto; sto.x=a0; sto.y=a1; sto.z=a2; sto.w=a3;
  *(float4*)(ts_aug_out + base + 4*t) = sto;
  // LN2 (ts_norm) -> tsn
  r = block_sum2(a0+a1+a2+a3, a0*a0+a1*a1+a2*a2+a3*a3, red);
  mu = r.x * (1.f/Dn); var = r.y * (1.f/Dn) - mu*mu;
  rs = 1.f / sqrtf(var + 1e-5f);
  g4 = *(const float4*)(tgp + 4*t); b4 = *(const float4*)(tbp + 4*t);
  float t0 = (a0-mu)*rs*g4.x + b4.x;
  float t1 = (a1-mu)*rs*g4.y + b4.y;
  float t2 = (a2-mu)*rs*g4.z + b4.z;
  float t3 = (a3-mu)*rs*g4.w + b4.w;
  // LN3 (pt_norm) -> ptn
  const float4 pv = *(const float4*)(pt + base + 4*t);
  r = block_sum2(pv.x+pv.y+pv.z+pv.w, pv.x*pv.x+pv.y*pv.y+pv.z*pv.z+pv.w*pv.w, red);
  mu = r.x * (1.f/Dn); var = r.y * (1.f/Dn) - mu*mu;
  rs = 1.f / sqrtf(var + 1e-5f);
  g4 = *(const float4*)(pgp + 4*t); b4 = *(const float4*)(pbp + 4*t);
  float p0 = (pv.x-mu)*rs*g4.x + b4.x;
  float p1 = (pv.y-mu)*rs*g4.y + b4.y;
  float p2 = (pv.z-mu)*rs*g4.z + b4.z;
  float p3 = (pv.w-mu)*rs*g4.w + b4.w;
  // store bf16 tsn|ptn into Xcat
  ushort4 pk;
  pk.x = f2bf(t0); pk.y = f2bf(t1); pk.z = f2bf(t2); pk.w = f2bf(t3);
  *(ushort4*)(Xcat + (size_t)row*2048 + 4*t) = pk;
  pk.x = f2bf(p0); pk.y = f2bf(p1); pk.z = f2bf(p2); pk.w = f2bf(p3);
  *(ushort4*)(Xcat + (size_t)row*2048 + Dn + 4*t) = pk;
  // cos -> gate
  float3 rr = block_sum3(t0*p0+t1*p1+t2*p2+t3*p3,
                         t0*t0+t1*t1+t2*t2+t3*t3,
                         p0*p0+p1*p1+p2*p2+p3*p3, red);
  if (t == 0){
    float cosv = rr.x / (fmaxf(sqrtf(rr.y), 1e-6f) * fmaxf(sqrtf(rr.z), 1e-6f));
    float ag = 0.5f * (1.f + cosv);
    float z = (ag - 0.72f) * 5.f;
    float focus = 0.2f + 0.8f * expf(-0.5f*z*z);
    gate[row] = ag * focus * stab[row];
  }
}

// ---------------- 128x128 bf16 MFMA GEMM, C = A @ Bt^T, fused epilogues ----------------
// A: [M][K] bf16 row-major, Bt: [1024][K] bf16 row-major (pre-transposed weights)
// mode 0: out0 = acc + sbias[n] + gate[m]*Wlast[n]         (shared)
// mode 1: dts[m,n] += blend*gate[m]*acc                    (ts_out RMW over ts_aug)
// mode 2: dpt[m,n] = ptin[m,n] + blend*gate[m]*acc         (pt_out)
__global__ __launch_bounds__(256) void k_gemm(
    const u16* __restrict__ A, const u16* __restrict__ Bt, int K, int mode,
    float* __restrict__ out0, const float* __restrict__ sbias, const float* __restrict__ Wlast,
    const float* __restrict__ gate, float* __restrict__ dts,
    const float* __restrict__ ptin, float* __restrict__ dpt, const float* __restrict__ bscale){
  __shared__ u16 As[128*32];
  __shared__ u16 Bs[128*32];
  int t = threadIdx.x; int lane = t & 63; int w = t >> 6;
  int m0 = blockIdx.x * 128, n0 = blockIdx.y * 128;
  f32x4 acc[4][4];
  #pragma unroll
  for (int i = 0; i < 4; i++)
    #pragma unroll
    for (int j = 0; j < 4; j++){ f32x4 z = {0.f,0.f,0.f,0.f}; acc[i][j] = z; }
  int qr = (w >> 1) * 64, qc = (w & 1) * 64;
  int r15 = lane & 15, quad = lane >> 4;
  // fragment LDS byte offsets (16B-chunk swizzle: col' = (col + ((row>>1)&3)*16) & 63)
  int a_off[4], b_off[4];
  #pragma unroll
  for (int i = 0; i < 4; i++){
    int rr = qr + i*16 + r15;
    a_off[i] = rr*64 + ((quad*16 + ((rr>>1)&3)*16) & 63);
    int cc = qc + i*16 + r15;
    b_off[i] = cc*64 + ((quad*16 + ((cc>>1)&3)*16) & 63);
  }
  // staging: 8192B tile as 512 x 16B chunks; thread t does chunks t and t+256
  int o0 = t*16, o1 = t*16 + 4096;
  int r0 = o0 >> 6, cb0 = o0 & 63;
  int r1 = o1 >> 6, cb1 = o1 & 63;
  int sw0 = r0*64 + ((cb0 + ((r0>>1)&3)*16) & 63);
  int sw1 = r1*64 + ((cb1 + ((r1>>1)&3)*16) & 63);
  const char* ga0 = (const char*)A + ((size_t)(m0+r0)*K)*2 + cb0;
  const char* ga1 = (const char*)A + ((size_t)(m0+r1)*K)*2 + cb1;
  const char* gb0 = (const char*)Bt + ((size_t)(n0+r0)*K)*2 + cb0;
  const char* gb1 = (const char*)Bt + ((size_t)(n0+r1)*K)*2 + cb1;
  char* la0 = (char*)As + sw0; char* la1 = (char*)As + sw1;
  char* lb0 = (char*)Bs + sw0; char* lb1 = (char*)Bs + sw1;
  int nk = K >> 5;
  for (int kk = 0; kk < nk; kk++){
    uint4 va0 = *(const uint4*)ga0; uint4 va1 = *(const uint4*)ga1;
    uint4 vb0 = *(const uint4*)gb0; uint4 vb1 = *(const uint4*)gb1;
    ga0 += 64; ga1 += 64; gb0 += 64; gb1 += 64;
    __syncthreads();
    *(uint4*)la0 = va0; *(uint4*)la1 = va1;
    *(uint4*)lb0 = vb0; *(uint4*)lb1 = vb1;
    __syncthreads();
    short8 af[4], bfr[4];
    #pragma unroll
    for (int i = 0; i < 4; i++) af[i]  = *(const short8*)((const char*)As + a_off[i]);
    #pragma unroll
    for (int j = 0; j < 4; j++) bfr[j] = *(const short8*)((const char*)Bs + b_off[j]);
    #pragma unroll
    for (int i = 0; i < 4; i++)
      #pragma unroll
      for (int j = 0; j < 4; j++)
        acc[i][j] = __builtin_amdgcn_mfma_f32_16x16x32_bf16(af[i], bfr[j], acc[i][j], 0, 0, 0);
  }
  float blend = 0.f;
  if (mode != 0) blend = 0.35f / (1.f + expf(-bscale[0]));
  #pragma unroll
  for (int i = 0; i < 4; i++){
    int rowb = m0 + qr + i*16 + quad*4;
    #pragma unroll
    for (int j = 0; j < 4; j++){
      int col = n0 + qc + j*16 + r15;
      #pragma unroll
      for (int rg = 0; rg < 4; rg++){
        int rw = rowb + rg;
        size_t idx = (size_t)rw * Dn + col;
        float v = acc[i][j][rg];
        if (mode == 0){
          out0[idx] = v + sbias[col] + gate[rw] * Wlast[col];
        } else if (mode == 1){
          dts[idx] = dts[idx] + blend * gate[rw] * v;
        } else {
          dpt[idx] = ptin[idx] + blend * gate[rw] * v;
        }
      }
    }
  }
}

// ---------------- causal pool (k=3) + diffs vs tsn/ptn, bf16 ----------------
__global__ __launch_bounds__(256) void k_pooldiff(const float* __restrict__ sh,
    const u16* __restrict__ Xcat, u16* __restrict__ Xts, u16* __restrict__ Xpt){
  int row = blockIdx.x; int s = row & 4095; int t = threadIdx.x;
  size_t base = (size_t)row * Dn + 4*t;
  int rm1 = (s >= 1) ? row-1 : row;
  int rm2 = (s >= 2) ? row-2 : rm1;
  float4 a = *(const float4*)(sh + base);
  float4 b = *(const float4*)(sh + (size_t)rm1*Dn + 4*t);
  float4 c = *(const float4*)(sh + (size_t)rm2*Dn + 4*t);
  float p0 = (a.x+b.x+c.x)*(1.f/3.f);
  float p1 = (a.y+b.y+c.y)*(1.f/3.f);
  float p2 = (a.z+b.z+c.z)*(1.f/3.f);
  float p3 = (a.w+b.w+c.w)*(1.f/3.f);
  ushort4 tn = *(const ushort4*)(Xcat + (size_t)row*2048 + 4*t);
  ushort4 pn = *(const ushort4*)(Xcat + (size_t)row*2048 + Dn + 4*t);
  ushort4 o;
  o.x = f2bf(p0 - bf2f(tn.x)); o.y = f2bf(p1 - bf2f(tn.y));
  o.z = f2bf(p2 - bf2f(tn.z)); o.w = f2bf(p3 - bf2f(tn.w));
  *(ushort4*)(Xts + base) = o;
  o.x = f2bf(p0 - bf2f(pn.x)); o.y = f2bf(p1 - bf2f(pn.y));
  o.z = f2bf(p2 - bf2f(pn.z)); o.w = f2bf(p3 - bf2f(pn.w));
  *(ushort4*)(Xpt + base) = o;
}

extern "C" void kernel_launch(void* const* d_in, const int* in_sizes, int n_in,
                              void* d_out, int out_size, void* d_ws, size_t ws_size,
                              hipStream_t stream){
  const float* pt   = (const float*)d_in[0];
  const float* ts   = (const float*)d_in[1];
  const float* pp   = (const float*)d_in[2];
  const float* cent = (const float*)d_in[3];
  const float* stab = (const float*)d_in[4];
  const float* aw   = (const float*)d_in[5];
  const float* ab   = (const float*)d_in[6];
  const float* ta   = (const float*)d_in[7];
  const float* tb   = (const float*)d_in[8];
  const float* og   = (const float*)d_in[9];
  const float* ob   = (const float*)d_in[10];
  const float* tg   = (const float*)d_in[11];
  const float* tbn  = (const float*)d_in[12];
  const float* pg   = (const float*)d_in[13];
  const float* pb   = (const float*)d_in[14];
  const float* sW   = (const float*)d_in[15];
  const float* sb   = (const float*)d_in[16];
  const float* tsW  = (const float*)d_in[17];
  const float* ptW  = (const float*)d_in[18];
  const float* bsc  = (const float*)d_in[19];
  float* out_ts = (float*)d_out;
  float* out_pt = out_ts + (size_t)BSn * Dn;

  char* wbase = (char*)d_ws; size_t off = 0;
  auto alloc = [&](size_t bytes) -> void* {
    void* p = wbase + off;
    off += (bytes + 255) & ~(size_t)255;
    return p;
  };
  float* scores = (float*)alloc((size_t)BSn * 4);
  int*   aidx   = (int*)  alloc(256);
  float* invZ   = (float*)alloc(256);
  float* transl = (float*)alloc((size_t)Bn*Kk*Dn * 4);
  float* gate   = (float*)alloc((size_t)BSn * 4);
  u16*   Xcat   = (u16*)  alloc((size_t)BSn * 2048 * 2);
  float* shmem  = (float*)alloc((size_t)BSn * Dn * 4);
  u16*   Xts    = (u16*)  alloc((size_t)BSn * Dn * 2);
  u16*   Xpt    = (u16*)  alloc((size_t)BSn * Dn * 2);
  u16*   WtS    = (u16*)  alloc((size_t)Dn * 2048 * 2);
  u16*   WtT    = (u16*)  alloc((size_t)Dn * Dn * 2);
  u16*   WtP    = (u16*)  alloc((size_t)Dn * Dn * 2);

  k_scores<<<BSn/4, 256, 0, stream>>>(pt, aw, ab, scores);
  k_top3<<<Bn, 256, 0, stream>>>(scores, aidx);
  k_adapter<<<Bn*Kk, 256, 0, stream>>>(pt, cent, ta, tb, pp, aidx, transl, invZ);
  k_transpose<<<dim3(64,32), 256, 0, stream>>>(sW, WtS, 2048);
  k_transpose<<<dim3(32,32), 256, 0, stream>>>(tsW, WtT, 1024);
  k_transpose<<<dim3(32,32), 256, 0, stream>>>(ptW, WtP, 1024);
  k_rows<<<BSn, 256, 0, stream>>>(ts, pt, stab, transl, aidx, invZ, pp,
                                  og, ob, tg, tbn, pg, pb, out_ts, Xcat, gate);
  k_gemm<<<dim3(BSn/128, Dn/128), 256, 0, stream>>>(Xcat, WtS, 2048, 0,
      shmem, sb, sW + (size_t)2048*Dn, gate, nullptr, nullptr, nullptr, bsc);
  k_pooldiff<<<BSn, 256, 0, stream>>>(shmem, Xcat, Xts, Xpt);
  k_gemm<<<dim3(BSn/128, Dn/128), 256, 0, stream>>>(Xts, WtT, 1024, 1,
      nullptr, nullptr, nullptr, gate, out_ts, nullptr, nullptr, bsc);
  k_gemm<<<dim3(BSn/128, Dn/128), 256, 0, stream>>>(Xpt, WtP, 1024, 2,
      nullptr, nullptr, nullptr, gate, nullptr, pt, out_pt, bsc);
}

// Round 2
// 1549.021 us; speedup vs baseline: 3.0366x; 3.0366x over previous
//
#include <hip/hip_runtime.h>

#define Bn 8
#define Sn 4096
#define Dn 1024
#define Mn 32
#define Kk 3
#define Rn 64
#define BSn (Bn*Sn)
#define NBK (Bn*Kk)   // 24

typedef unsigned short u16;
typedef short short8 __attribute__((ext_vector_type(8)));
typedef float f32x4 __attribute__((ext_vector_type(4)));

__device__ __forceinline__ u16 f2bf(float f){
  unsigned u = __builtin_bit_cast(unsigned, f);
  u += 0x7fffu + ((u >> 16) & 1u);          // RNE
  return (u16)(u >> 16);
}
__device__ __forceinline__ float bf2f(u16 h){
  unsigned u = ((unsigned)h) << 16;
  return __builtin_bit_cast(float, u);
}

__device__ __forceinline__ void cp16(const void* g, void* l){
  __builtin_amdgcn_global_load_lds(
      (const __attribute__((address_space(1))) void*)g,
      (__attribute__((address_space(3))) void*)l, 16, 0, 0);
}

__device__ __forceinline__ float2 block_sum2(float a, float b, float* red){
  #pragma unroll
  for (int off = 32; off > 0; off >>= 1){
    a += __shfl_down(a, off, 64);
    b += __shfl_down(b, off, 64);
  }
  int lane = threadIdx.x & 63, w = threadIdx.x >> 6;
  if (lane == 0){ red[w] = a; red[4+w] = b; }
  __syncthreads();
  float2 r;
  r.x = red[0]+red[1]+red[2]+red[3];
  r.y = red[4]+red[5]+red[6]+red[7];
  __syncthreads();
  return r;
}

__device__ __forceinline__ float3 block_sum3(float a, float b, float c, float* red){
  #pragma unroll
  for (int off = 32; off > 0; off >>= 1){
    a += __shfl_down(a, off, 64);
    b += __shfl_down(b, off, 64);
    c += __shfl_down(c, off, 64);
  }
  int lane = threadIdx.x & 63, w = threadIdx.x >> 6;
  if (lane == 0){ red[w] = a; red[4+w] = b; red[8+w] = c; }
  __syncthreads();
  float3 r;
  r.x = red[0]+red[1]+red[2]+red[3];
  r.y = red[4]+red[5]+red[6]+red[7];
  r.z = red[8]+red[9]+red[10]+red[11];
  __syncthreads();
  return r;
}

// ---------------- scores = pt_hidden @ anchor_w + anchor_b ----------------
__global__ __launch_bounds__(256) void k_scores(const float* __restrict__ pt,
    const float* __restrict__ aw, const float* __restrict__ ab, float* __restrict__ scores){
  int lane = threadIdx.x & 63, w = threadIdx.x >> 6;
  int row = blockIdx.x * 4 + w;
  const float4* x  = (const float4*)(pt + (size_t)row * Dn);
  const float4* wv = (const float4*)aw;
  float acc = 0.f;
  #pragma unroll
  for (int c = 0; c < 4; c++){
    int i = c * 64 + lane;
    float4 a = x[i], b = wv[i];
    acc += a.x*b.x + a.y*b.y + a.z*b.z + a.w*b.w;
  }
  #pragma unroll
  for (int off = 32; off > 0; off >>= 1) acc += __shfl_down(acc, off, 64);
  if (lane == 0) scores[row] = acc + ab[0];
}

// ---------------- top-3 per batch ----------------
__global__ __launch_bounds__(256) void k_top3(const float* __restrict__ scores, int* __restrict__ aidx){
  __shared__ float tv[256*3];
  __shared__ int   ti[256*3];
  int b = blockIdx.x, t = threadIdx.x;
  float v[3] = {-1e38f, -1e38f, -1e38f};
  int  id[3] = {0x7fffffff, 0x7fffffff, 0x7fffffff};
  for (int s = t; s < Sn; s += 256){
    float sc = scores[b*Sn + s];
    if (sc > v[0] || (sc == v[0] && s < id[0])){ v[2]=v[1]; id[2]=id[1]; v[1]=v[0]; id[1]=id[0]; v[0]=sc; id[0]=s; }
    else if (sc > v[1] || (sc == v[1] && s < id[1])){ v[2]=v[1]; id[2]=id[1]; v[1]=sc; id[1]=s; }
    else if (sc > v[2] || (sc == v[2] && s < id[2])){ v[2]=sc; id[2]=s; }
  }
  for (int j = 0; j < 3; j++){ tv[t*3+j] = v[j]; ti[t*3+j] = id[j]; }
  __syncthreads();
  if (t == 0){
    float bv[3] = {-1e38f, -1e38f, -1e38f};
    int   bi[3] = {0x7fffffff, 0x7fffffff, 0x7fffffff};
    for (int c = 0; c < 256*3; c++){
      float sc = tv[c]; int ii = ti[c];
      if (sc > bv[0] || (sc == bv[0] && ii < bi[0])){ bv[2]=bv[1]; bi[2]=bi[1]; bv[1]=bv[0]; bi[1]=bi[0]; bv[0]=sc; bi[0]=ii; }
      else if (sc > bv[1] || (sc == bv[1] && ii < bi[1])){ bv[2]=bv[1]; bi[2]=bi[1]; bv[1]=sc; bi[1]=ii; }
      else if (sc > bv[2] || (sc == bv[2] && ii < bi[2])){ bv[2]=sc; bi[2]=ii; }
    }
    for (int j = 0; j < 3; j++) aidx[b*3+j] = bi[j];
  }
}

// ---------------- adapter phase A: per (b,k): gather anchor, softmax weights, invZ ----------------
__global__ __launch_bounds__(256) void k_adapter_w(const float* __restrict__ pt,
    const float* __restrict__ cent, const float* __restrict__ pp, const int* __restrict__ aidx,
    float* __restrict__ A24, float* __restrict__ gw, float* __restrict__ invZ){
  __shared__ float a_lds[Dn];
  __shared__ float logitv[Mn];
  __shared__ float red[12];
  int bk = blockIdx.x; int b = bk / Kk;
  int t = threadIdx.x;
  int p = aidx[bk];
  const float* arow = pt + ((size_t)b*Sn + p) * Dn;
  for (int d = t; d < Dn; d += 256){ float v = arow[d]; a_lds[d] = v; A24[(size_t)bk*Dn + d] = v; }
  __syncthreads();
  float ss = 0.f;
  for (int d = t; d < Dn; d += 256){ float v = a_lds[d]; ss += v*v; }
  float2 rr0 = block_sum2(ss, 0.f, red);
  float na = fmaxf(sqrtf(rr0.x), 1e-6f);
  int lane = t & 63, w = t >> 6;
  for (int mi = 0; mi < 8; mi++){
    int m = w*8 + mi;
    const float* c = cent + (size_t)m * Dn;
    float dt = 0.f, cs = 0.f;
    for (int d = lane; d < Dn; d += 64){ float cv = c[d]; dt += a_lds[d]*cv; cs += cv*cv; }
    #pragma unroll
    for (int off = 32; off > 0; off >>= 1){ dt += __shfl_down(dt, off, 64); cs += __shfl_down(cs, off, 64); }
    if (lane == 0){ float nc = fmaxf(sqrtf(cs), 1e-6f); logitv[m] = dt / (na * nc); }
  }
  __syncthreads();
  if (t == 0){
    float mx = -1e30f;
    for (int m = 0; m < Mn; m++) mx = fmaxf(mx, logitv[m]);
    float sm = 0.f, e[Mn];
    for (int m = 0; m < Mn; m++){ e[m] = expf(logitv[m]-mx); sm += e[m]; }
    float inv = 1.f / sm;
    for (int m = 0; m < Mn; m++) gw[bk*Mn + m] = e[m] * inv;
  }
  // spread normalizer Z
  {
    float zp = 0.f; float ppp = pp[p];
    for (int s2 = t; s2 < Sn; s2 += 256){
      float dd = fabsf(pp[s2] - ppp);
      if (dd <= 8.0f) zp += expf(-dd * 0.125f);
    }
    float2 zr = block_sum2(zp, 0.f, red);
    if (t == 0) invZ[bk] = 1.f / zr.x;
  }
}

// ---------------- low partials: block (dc, m): part[bk][m][dc][r] = sum_{d in chunk} a[bk][d]*ta[m][d][r]
__global__ __launch_bounds__(256) void k_lowpart(const float* __restrict__ ta,
    const float* __restrict__ A24, float* __restrict__ part_low){
  __shared__ float ta_s[64*64];       // [d][r]
  __shared__ float a_s[NBK*64];       // [bk][d]
  int dc = blockIdx.x, m = blockIdx.y;
  int t = threadIdx.x;
  int d0 = dc * 64;
  const float4* src = (const float4*)(ta + ((size_t)m*Dn + d0) * Rn);
  float4* dst = (float4*)ta_s;
  #pragma unroll
  for (int c = 0; c < 4; c++) dst[t + c*256] = src[t + c*256];
  for (int idx = t; idx < NBK*64; idx += 256){
    int bk = idx >> 6, dl = idx & 63;
    a_s[idx] = A24[(size_t)bk*Dn + d0 + dl];
  }
  __syncthreads();
  int r = t & 63, g = t >> 6;
  #pragma unroll
  for (int j = 0; j < 6; j++){
    int bk = g*6 + j;
    float acc = 0.f;
    #pragma unroll 8
    for (int d = 0; d < 64; d++) acc += a_s[bk*64 + d] * ta_s[d*64 + r];
    part_low[(((size_t)bk*Mn + m)*16 + dc)*64 + r] = acc;
  }
}

// ---------------- low final: low[bk][r] = sum_m w * sum_dc part ----------------
__global__ __launch_bounds__(64) void k_lowfin(const float* __restrict__ part_low,
    const float* __restrict__ gw, float* __restrict__ lowb){
  int bk = blockIdx.x, r = threadIdx.x;
  float acc = 0.f;
  for (int m = 0; m < Mn; m++){
    float s = 0.f;
    #pragma unroll
    for (int dc = 0; dc < 16; dc++)
      s += part_low[(((size_t)bk*Mn + m)*16 + dc)*64 + r];
    acc += gw[bk*Mn + m] * s;
  }
  lowb[bk*64 + r] = acc;
}

// ---------------- translated partials: block (dc, m): transp[bk][m][d] = sum_r tb[m][d][r]*low[bk][r]
__global__ __launch_bounds__(256) void k_transpart(const float* __restrict__ tb,
    const float* __restrict__ lowb, float* __restrict__ transp){
  __shared__ float tb_t[64*65];       // [r][d], padded
  __shared__ float low_s[NBK*64];
  int dc = blockIdx.x, m = blockIdx.y;
  int t = threadIdx.x;
  int d0 = dc * 64;
  const float* src = tb + ((size_t)m*Dn + d0) * Rn;
  for (int idx = t; idx < 4096; idx += 256){
    int d = idx >> 6, r = idx & 63;
    tb_t[r*65 + d] = src[idx];
  }
  for (int idx = t; idx < NBK*64; idx += 256) low_s[idx] = lowb[idx];
  __syncthreads();
  int dl = t & 63, g = t >> 6;
  #pragma unroll
  for (int j = 0; j < 6; j++){
    int bk = g*6 + j;
    float acc = 0.f;
    #pragma unroll 8
    for (int r = 0; r < 64; r++) acc += tb_t[r*65 + dl] * low_s[bk*64 + r];
    transp[((size_t)bk*Mn + m)*Dn + d0 + dl] = acc;
  }
}

// ---------------- translated final: transl[bk][d] = sum_m w*transp ----------------
__global__ __launch_bounds__(256) void k_transfin(const float* __restrict__ transp,
    const float* __restrict__ gw, float* __restrict__ transl){
  int bk = blockIdx.x, t = threadIdx.x;
  for (int d = t; d < Dn; d += 256){
    float acc = 0.f;
    #pragma unroll 8
    for (int m = 0; m < Mn; m++)
      acc += gw[bk*Mn + m] * transp[((size_t)bk*Mn + m)*Dn + d];
    transl[(size_t)bk*Dn + d] = acc;
  }
}

// ---------------- transpose f32 [Ks][1024] -> bf16 [1024][Ks] ----------------
__global__ __launch_bounds__(256) void k_transpose(const float* __restrict__ src,
    u16* __restrict__ dst, int Ks){
  __shared__ float tile[32][33];
  int kb = blockIdx.x * 32, nb = blockIdx.y * 32;
  int tx = threadIdx.x & 31, ty = threadIdx.x >> 5;
  #pragma unroll
  for (int r = 0; r < 32; r += 8)
    tile[ty+r][tx] = src[(size_t)(kb+ty+r) * Dn + nb + tx];
  __syncthreads();
  #pragma unroll
  for (int r = 0; r < 32; r += 8)
    dst[(size_t)(nb+ty+r) * Ks + kb + tx] = f2bf(tile[tx][ty+r]);
}

// ---------------- per-row: spread update + 3 LN + gate ----------------
__global__ __launch_bounds__(256) void k_rows(
    const float* __restrict__ ts, const float* __restrict__ pt,
    const float* __restrict__ stab, const float* __restrict__ transl,
    const int* __restrict__ aidx, const float* __restrict__ invZ,
    const float* __restrict__ pp,
    const float* __restrict__ og, const float* __restrict__ ob,
    const float* __restrict__ tgp, const float* __restrict__ tbp,
    const float* __restrict__ pgp, const float* __restrict__ pbp,
    float* __restrict__ ts_aug_out, u16* __restrict__ Xcat, float* __restrict__ gate){
  __shared__ float red[12];
  int row = blockIdx.x; int b = row >> 12; int s = row & 4095;
  int t = threadIdx.x;
  size_t base = (size_t)row * Dn;
  const float4 xin = *(const float4*)(ts + base + 4*t);
  float x0 = xin.x, x1 = xin.y, x2 = xin.z, x3 = xin.w;
  float pps = pp[s];
  for (int k = 0; k < Kk; k++){
    int p = aidx[b*Kk + k];
    float dd = fabsf(pps - pp[p]);
    if (dd <= 8.0f){
      float coef = expf(-dd * 0.125f) * invZ[b*Kk + k];
      const float4 tr = *(const float4*)(transl + ((size_t)(b*Kk + k)) * Dn + 4*t);
      x0 += coef*tr.x; x1 += coef*tr.y; x2 += coef*tr.z; x3 += coef*tr.w;
    }
  }
  float2 r = block_sum2(x0+x1+x2+x3, x0*x0+x1*x1+x2*x2+x3*x3, red);
  float mu = r.x * (1.f/Dn); float var = r.y * (1.f/Dn) - mu*mu;
  float rs = 1.f / sqrtf(var + 1e-5f);
  float4 g4 = *(const float4*)(og + 4*t), b4 = *(const float4*)(ob + 4*t);
  float a0 = (x0-mu)*rs*g4.x + b4.x;
  float a1 = (x1-mu)*rs*g4.y + b4.y;
  float a2 = (x2-mu)*rs*g4.z + b4.z;
  float a3 = (x3-mu)*rs*g4.w + b4.w;
  float4 sto; sto.x=a0; sto.y=a1; sto.z=a2; sto.w=a3;
  *(float4*)(ts_aug_out + base + 4*t) = sto;
  r = block_sum2(a0+a1+a2+a3, a0*a0+a1*a1+a2*a2+a3*a3, red);
  mu = r.x * (1.f/Dn); var = r.y * (1.f/Dn) - mu*mu;
  rs = 1.f / sqrtf(var + 1e-5f);
  g4 = *(const float4*)(tgp + 4*t); b4 = *(const float4*)(tbp + 4*t);
  float t0 = (a0-mu)*rs*g4.x + b4.x;
  float t1 = (a1-mu)*rs*g4.y + b4.y;
  float t2 = (a2-mu)*rs*g4.z + b4.z;
  float t3 = (a3-mu)*rs*g4.w + b4.w;
  const float4 pv = *(const float4*)(pt + base + 4*t);
  r = block_sum2(pv.x+pv.y+pv.z+pv.w, pv.x*pv.x+pv.y*pv.y+pv.z*pv.z+pv.w*pv.w, red);
  mu = r.x * (1.f/Dn); var = r.y * (1.f/Dn) - mu*mu;
  rs = 1.f / sqrtf(var + 1e-5f);
  g4 = *(const float4*)(pgp + 4*t); b4 = *(const float4*)(pbp + 4*t);
  float p0 = (pv.x-mu)*rs*g4.x + b4.x;
  float p1 = (pv.y-mu)*rs*g4.y + b4.y;
  float p2 = (pv.z-mu)*rs*g4.z + b4.z;
  float p3 = (pv.w-mu)*rs*g4.w + b4.w;
  ushort4 pk;
  pk.x = f2bf(t0); pk.y = f2bf(t1); pk.z = f2bf(t2); pk.w = f2bf(t3);
  *(ushort4*)(Xcat + (size_t)row*2048 + 4*t) = pk;
  pk.x = f2bf(p0); pk.y = f2bf(p1); pk.z = f2bf(p2); pk.w = f2bf(p3);
  *(ushort4*)(Xcat + (size_t)row*2048 + Dn + 4*t) = pk;
  float3 rr = block_sum3(t0*p0+t1*p1+t2*p2+t3*p3,
                         t0*t0+t1*t1+t2*t2+t3*t3,
                         p0*p0+p1*p1+p2*p2+p3*p3, red);
  if (t == 0){
    float cosv = rr.x / (fmaxf(sqrtf(rr.y), 1e-6f) * fmaxf(sqrtf(rr.z), 1e-6f));
    float ag = 0.5f * (1.f + cosv);
    float z = (ag - 0.72f) * 5.f;
    float focus = 0.2f + 0.8f * expf(-0.5f*z*z);
    gate[row] = ag * focus * stab[row];
  }
}

// ---------------- 128x128 bf16 MFMA GEMM (m97-style global_load_lds staging) ----------------
// A: [M][K] bf16 row-major, Bt: [1024][K] bf16 row-major.
// LDS: linear rows of 64B, 16B-chunk XOR swizzle: chunk (row, gc) stored at col (gc ^ (row&3)).
// mode 0: out0 = acc + sbias[n] + gate[m]*Wlast[n]
// mode 1: dts[m,n] += blend*gate[m]*acc
// mode 2: dpt[m,n] = ptin[m,n] + blend*gate[m]*acc
__global__ __launch_bounds__(256) void k_gemm(
    const u16* __restrict__ A, const u16* __restrict__ Bt, int K, int mode,
    float* __restrict__ out0, const float* __restrict__ sbias, const float* __restrict__ Wlast,
    const float* __restrict__ gate, float* __restrict__ dts,
    const float* __restrict__ ptin, float* __restrict__ dpt, const float* __restrict__ bscale){
  __shared__ u16 As[128*32];
  __shared__ u16 Bs[128*32];
  int t = threadIdx.x; int lane = t & 63; int w = t >> 6;
  int m0 = blockIdx.x * 128, n0 = blockIdx.y * 128;
  f32x4 acc[4][4];
  #pragma unroll
  for (int i = 0; i < 4; i++)
    #pragma unroll
    for (int j = 0; j < 4; j++){ f32x4 z = {0.f,0.f,0.f,0.f}; acc[i][j] = z; }
  int qr = (w >> 1) * 64, qc = (w & 1) * 64;
  int r15 = lane & 15, quad = lane >> 4;
  // fragment LDS byte offsets with XOR swizzle
  int a_off[4], b_off[4];
  #pragma unroll
  for (int i = 0; i < 4; i++){
    int rr = qr + i*16 + r15;
    a_off[i] = rr*64 + ((quad ^ (rr&3)) * 16);
    int cc = qc + i*16 + r15;
    b_off[i] = cc*64 + ((quad ^ (cc&3)) * 16);
  }
  // staging: thread t handles LDS chunks t and t+256 (contiguous lane order for global_load_lds)
  int rr0 = t >> 2;             // rows 0..63
  int gc0 = (t & 3) ^ (rr0 & 3);
  int rr1 = rr0 + 64;           // rows 64..127, (rr1&3)==(rr0&3)
  const char* ga0 = (const char*)A + ((size_t)(m0+rr0)*K)*2 + gc0*16;
  const char* ga1 = (const char*)A + ((size_t)(m0+rr1)*K)*2 + gc0*16;
  const char* gb0 = (const char*)Bt + ((size_t)(n0+rr0)*K)*2 + gc0*16;
  const char* gb1 = (const char*)Bt + ((size_t)(n0+rr1)*K)*2 + gc0*16;
  char* la0 = (char*)As + t*16; char* la1 = la0 + 4096;
  char* lb0 = (char*)Bs + t*16; char* lb1 = lb0 + 4096;
  int nk = K >> 5;
  for (int kk = 0; kk < nk; kk++){
    __syncthreads();            // all waves done reading previous tile
    cp16(ga0, la0); cp16(ga1, la1);
    cp16(gb0, lb0); cp16(gb1, lb1);
    ga0 += 64; ga1 += 64; gb0 += 64; gb1 += 64;
    __syncthreads();            // vmcnt drained; tile visible
    short8 af[4], bfr[4];
    #pragma unroll
    for (int i = 0; i < 4; i++) af[i]  = *(const short8*)((const char*)As + a_off[i]);
    #pragma unroll
    for (int j = 0; j < 4; j++) bfr[j] = *(const short8*)((const char*)Bs + b_off[j]);
    #pragma unroll
    for (int i = 0; i < 4; i++)
      #pragma unroll
      for (int j = 0; j < 4; j++)
        acc[i][j] = __builtin_amdgcn_mfma_f32_16x16x32_bf16(af[i], bfr[j], acc[i][j], 0, 0, 0);
  }
  float blend = 0.f;
  if (mode != 0) blend = 0.35f / (1.f + expf(-bscale[0]));
  #pragma unroll
  for (int i = 0; i < 4; i++){
    int rowb = m0 + qr + i*16 + quad*4;
    #pragma unroll
    for (int j = 0; j < 4; j++){
      int col = n0 + qc + j*16 + r15;
      #pragma unroll
      for (int rg = 0; rg < 4; rg++){
        int rw = rowb + rg;
        size_t idx = (size_t)rw * Dn + col;
        float v = acc[i][j][rg];
        if (mode == 0){
          out0[idx] = v + sbias[col] + gate[rw] * Wlast[col];
        } else if (mode == 1){
          dts[idx] = dts[idx] + blend * gate[rw] * v;
        } else {
          dpt[idx] = ptin[idx] + blend * gate[rw] * v;
        }
      }
    }
  }
}

// ---------------- causal pool (k=3) + diffs vs tsn/ptn, bf16 ----------------
__global__ __launch_bounds__(256) void k_pooldiff(const float* __restrict__ sh,
    const u16* __restrict__ Xcat, u16* __restrict__ Xts, u16* __restrict__ Xpt){
  int row = blockIdx.x; int s = row & 4095; int t = threadIdx.x;
  size_t base = (size_t)row * Dn + 4*t;
  int rm1 = (s >= 1) ? row-1 : row;
  int rm2 = (s >= 2) ? row-2 : rm1;
  float4 a = *(const float4*)(sh + base);
  float4 b = *(const float4*)(sh + (size_t)rm1*Dn + 4*t);
  float4 c = *(const float4*)(sh + (size_t)rm2*Dn + 4*t);
  float p0 = (a.x+b.x+c.x)*(1.f/3.f);
  float p1 = (a.y+b.y+c.y)*(1.f/3.f);
  float p2 = (a.z+b.z+c.z)*(1.f/3.f);
  float p3 = (a.w+b.w+c.w)*(1.f/3.f);
  ushort4 tn = *(const ushort4*)(Xcat + (size_t)row*2048 + 4*t);
  ushort4 pn = *(const ushort4*)(Xcat + (size_t)row*2048 + Dn + 4*t);
  ushort4 o;
  o.x = f2bf(p0 - bf2f(tn.x)); o.y = f2bf(p1 - bf2f(tn.y));
  o.z = f2bf(p2 - bf2f(tn.z)); o.w = f2bf(p3 - bf2f(tn.w));
  *(ushort4*)(Xts + base) = o;
  o.x = f2bf(p0 - bf2f(pn.x)); o.y = f2bf(p1 - bf2f(pn.y));
  o.z = f2bf(p2 - bf2f(pn.z)); o.w = f2bf(p3 - bf2f(pn.w));
  *(ushort4*)(Xpt + base) = o;
}

extern "C" void kernel_launch(void* const* d_in, const int* in_sizes, int n_in,
                              void* d_out, int out_size, void* d_ws, size_t ws_size,
                              hipStream_t stream){
  const float* pt   = (const float*)d_in[0];
  const float* ts   = (const float*)d_in[1];
  const float* pp   = (const float*)d_in[2];
  const float* cent = (const float*)d_in[3];
  const float* stab = (const float*)d_in[4];
  const float* aw   = (const float*)d_in[5];
  const float* ab   = (const float*)d_in[6];
  const float* ta   = (const float*)d_in[7];
  const float* tb   = (const float*)d_in[8];
  const float* og   = (const float*)d_in[9];
  const float* ob   = (const float*)d_in[10];
  const float* tg   = (const float*)d_in[11];
  const float* tbn  = (const float*)d_in[12];
  const float* pg   = (const float*)d_in[13];
  const float* pb   = (const float*)d_in[14];
  const float* sW   = (const float*)d_in[15];
  const float* sb   = (const float*)d_in[16];
  const float* tsW  = (const float*)d_in[17];
  const float* ptW  = (const float*)d_in[18];
  const float* bsc  = (const float*)d_in[19];
  float* out_ts = (float*)d_out;
  float* out_pt = out_ts + (size_t)BSn * Dn;

  char* wbase = (char*)d_ws; size_t off = 0;
  auto alloc = [&](size_t bytes) -> void* {
    void* p = wbase + off;
    off += (bytes + 255) & ~(size_t)255;
    return p;
  };
  float* scores  = (float*)alloc((size_t)BSn * 4);
  int*   aidx    = (int*)  alloc(256);
  float* invZ    = (float*)alloc(256);
  float* transl  = (float*)alloc((size_t)NBK*Dn * 4);
  float* gate    = (float*)alloc((size_t)BSn * 4);
  float* A24     = (float*)alloc((size_t)NBK*Dn * 4);
  float* gw      = (float*)alloc((size_t)NBK*Mn * 4);
  float* part_low= (float*)alloc((size_t)NBK*Mn*16*64 * 4);
  float* lowb    = (float*)alloc((size_t)NBK*64 * 4);
  float* transp  = (float*)alloc((size_t)NBK*Mn*Dn * 4);
  u16*   Xcat    = (u16*)  alloc((size_t)BSn * 2048 * 2);
  float* shmem   = (float*)alloc((size_t)BSn * Dn * 4);
  u16*   Xts     = (u16*)  alloc((size_t)BSn * Dn * 2);
  u16*   Xpt     = (u16*)  alloc((size_t)BSn * Dn * 2);
  u16*   WtS     = (u16*)  alloc((size_t)Dn * 2048 * 2);
  u16*   WtT     = (u16*)  alloc((size_t)Dn * Dn * 2);
  u16*   WtP     = (u16*)  alloc((size_t)Dn * Dn * 2);

  k_scores<<<BSn/4, 256, 0, stream>>>(pt, aw, ab, scores);
  k_top3<<<Bn, 256, 0, stream>>>(scores, aidx);
  k_adapter_w<<<NBK, 256, 0, stream>>>(pt, cent, pp, aidx, A24, gw, invZ);
  k_lowpart<<<dim3(16, Mn), 256, 0, stream>>>(ta, A24, part_low);
  k_lowfin<<<NBK, 64, 0, stream>>>(part_low, gw, lowb);
  k_transpart<<<dim3(16, Mn), 256, 0, stream>>>(tb, lowb, transp);
  k_transfin<<<NBK, 256, 0, stream>>>(transp, gw, transl);
  k_transpose<<<dim3(64,32), 256, 0, stream>>>(sW, WtS, 2048);
  k_transpose<<<dim3(32,32), 256, 0, stream>>>(tsW, WtT, 1024);
  k_transpose<<<dim3(32,32), 256, 0, stream>>>(ptW, WtP, 1024);
  k_rows<<<BSn, 256, 0, stream>>>(ts, pt, stab, transl, aidx, invZ, pp,
                                  og, ob, tg, tbn, pg, pb, out_ts, Xcat, gate);
  k_gemm<<<dim3(BSn/128, Dn/128), 256, 0, stream>>>(Xcat, WtS, 2048, 0,
      shmem, sb, sW + (size_t)2048*Dn, gate, nullptr, nullptr, nullptr, bsc);
  k_pooldiff<<<BSn, 256, 0, stream>>>(shmem, Xcat, Xts, Xpt);
  k_gemm<<<dim3(BSn/128, Dn/128), 256, 0, stream>>>(Xts, WtT, 1024, 1,
      nullptr, nullptr, nullptr, gate, out_ts, nullptr, nullptr, bsc);
  k_gemm<<<dim3(BSn/128, Dn/128), 256, 0, stream>>>(Xpt, WtP, 1024, 2,
      nullptr, nullptr, nullptr, gate, nullptr, pt, out_pt, bsc);
}